// Round 10
// baseline (161.416 us; speedup 1.0000x reference)
//
#include <hip/hip_runtime.h>
#include <hip/hip_fp16.h>
#include <stdint.h>

// ---------------------------------------------------------------------------
// 2D DCT-II (unnormalized, 4096x4096 fp32), FFT path, v11:
//   v10 (fp16 intermediate V, -8 us) x v9 (fused column pass) combined:
//   1. dct_rows : x  -> ws  (V as fp16, 32 MB; column-Makhoul folded into
//                  the output row index: row 2b -> b, row 2b+1 -> 4095-b)
//   2. col_dct  : ws -> out (one block = 4 complex cols x ALL 4096 rows in
//                  128 KB LDS; radix-16^3 Stockham FFT over rows;
//                  Hermitian/expk epilogue; fp32 final Z)
//   H intermediate GONE (no B1 round-trip, no H rounding); array traffic
//   320 MB (v10) -> 192 MB. V lives in workspace (not d_out) because fp16 V
//   packed at the base of d_out would alias other blocks' fp32 writes.
//   Harness fills run at 6.6 TB/s (83% peak) and are fixed overhead.
// ---------------------------------------------------------------------------

#define NF 4096

__device__ __forceinline__ int physi(int e) { return e ^ ((e >> 4) & 15); }

// LDS index for col_dct: buf[(n,c)] with 2-bit XOR bank swizzle (v9, verified).
__device__ __forceinline__ int cfi(int n, int c) {
    return (n << 2) | (c ^ (((n >> 2) ^ (n >> 4)) & 3));
}

__device__ __forceinline__ float2 cadd(float2 a, float2 b) {
    float2 r; r.x = a.x + b.x; r.y = a.y + b.y; return r;
}
__device__ __forceinline__ float2 csub(float2 a, float2 b) {
    float2 r; r.x = a.x - b.x; r.y = a.y - b.y; return r;
}
__device__ __forceinline__ float2 cmulc(float2 a, float2 b) {
    float2 r; r.x = a.x * b.x - a.y * b.y; r.y = a.x * b.y + a.y * b.x; return r;
}
__device__ __forceinline__ float2 rotm(float2 a) {  // -i * a
    float2 r; r.x = a.y; r.y = -a.x; return r;
}

// tw layout (float2 units):
//   [0,64)      radix-8 Ls=8 table (legacy slot, unused in v11)
//   [64,320)    radix-16 stage-1    w[p][u] = exp(-2pi*i*p*u/256)  p,u<16
//   [320,4416)  radix-16 stage-2    w[p][u] = exp(-2pi*i*p*u/4096) p<256,u<16
// ek: expk[k] = (cos(pi*k/8192), sin(pi*k/8192)), 4096 entries.
__global__ __launch_bounds__(256) void setup_tables(float* __restrict__ tw,
                                                    float* __restrict__ ek) {
    int idx = blockIdx.x * 256 + threadIdx.x;
    if (idx < 4416) {
        int p, u; float denom;
        if (idx < 64)       { p = idx >> 3;         u = idx & 7;  denom = 64.0f; }
        else if (idx < 320) { int r = idx - 64;  p = r >> 4; u = r & 15; denom = 256.0f; }
        else                { int r = idx - 320; p = r >> 4; u = r & 15; denom = 4096.0f; }
        float phi = (float)(p * u) * (6.283185307179586f / denom);
        float s, c; __sincosf(phi, &s, &c);
        tw[2 * idx]     = c;
        tw[2 * idx + 1] = -s;
    } else if (idx < 8512) {
        int k = idx - 4416;
        float th = (float)k * (3.141592653589793f / 8192.0f);
        float s, c; __sincosf(th, &s, &c);
        ek[2 * k]     = c;
        ek[2 * k + 1] = s;
    }
}

#define RADIX8(Xv, E0, E1, E2, E3, O0, g1, g2, g3)                             \
    float2 t0 = cadd(Xv[0], Xv[4]), t1 = csub(Xv[0], Xv[4]);                   \
    float2 t2 = cadd(Xv[2], Xv[6]), t3 = csub(Xv[2], Xv[6]);                   \
    float2 E0 = cadd(t0, t2), E2 = csub(t0, t2);                               \
    float2 r3 = rotm(t3);                                                      \
    float2 E1 = cadd(t1, r3), E3 = csub(t1, r3);                               \
    float2 s0 = cadd(Xv[1], Xv[5]), s1 = csub(Xv[1], Xv[5]);                   \
    float2 s2 = cadd(Xv[3], Xv[7]), s3 = csub(Xv[3], Xv[7]);                   \
    float2 O0 = cadd(s0, s2), O2 = csub(s0, s2);                               \
    float2 r7 = rotm(s3);                                                      \
    float2 O1 = cadd(s1, r7), O3 = csub(s1, r7);                               \
    const float SQ = 0.7071067811865476f;                                      \
    float2 g1; g1.x = SQ * (O1.x + O1.y); g1.y = SQ * (O1.y - O1.x);           \
    float2 g2 = rotm(O2);                                                      \
    float2 g3; g3.x = SQ * (O3.y - O3.x); g3.y = -SQ * (O3.x + O3.y);

// Full radix-8 butterfly to out[8] (self-scoped, reusable in one scope).
#define RADIX8_OUT(Xv, Ov)                                                     \
    {                                                                          \
        RADIX8(Xv, E0, E1, E2, E3, O0, g1, g2, g3)                             \
        Ov[0] = cadd(E0, O0); Ov[1] = cadd(E1, g1);                            \
        Ov[2] = cadd(E2, g2); Ov[3] = cadd(E3, g3);                            \
        Ov[4] = csub(E0, O0); Ov[5] = csub(E1, g1);                            \
        Ov[6] = csub(E2, g2); Ov[7] = csub(E3, g3);                            \
    }

// In-place 16-pt DFT: X[i] = E[i&7] +/- W16^i * O[i&7], E/O = DFT8(even/odd).
__device__ __forceinline__ void dft16(float2* x) {
    float2 E[8], O[8];
    {
        float2 a[8];
        #pragma unroll
        for (int m = 0; m < 8; ++m) a[m] = x[2 * m];
        RADIX8_OUT(a, E)
    }
    {
        float2 a[8];
        #pragma unroll
        for (int m = 0; m < 8; ++m) a[m] = x[2 * m + 1];
        RADIX8_OUT(a, O)
    }
    const float2 W1 = { 0.9238795325112867f, -0.3826834323650898f};
    const float2 W2 = { 0.7071067811865476f, -0.7071067811865476f};
    const float2 W3 = { 0.3826834323650898f, -0.9238795325112867f};
    const float2 W5 = {-0.3826834323650898f, -0.9238795325112867f};
    const float2 W6 = {-0.7071067811865476f, -0.7071067811865476f};
    const float2 W7 = {-0.9238795325112867f, -0.3826834323650898f};
    float2 t;
    x[0] = cadd(E[0], O[0]);  x[8]  = csub(E[0], O[0]);
    t = cmulc(O[1], W1); x[1] = cadd(E[1], t); x[9]  = csub(E[1], t);
    t = cmulc(O[2], W2); x[2] = cadd(E[2], t); x[10] = csub(E[2], t);
    t = cmulc(O[3], W3); x[3] = cadd(E[3], t); x[11] = csub(E[3], t);
    t = rotm(O[4]);      x[4] = cadd(E[4], t); x[12] = csub(E[4], t);
    t = cmulc(O[5], W5); x[5] = cadd(E[5], t); x[13] = csub(E[5], t);
    t = cmulc(O[6], W6); x[6] = cadd(E[6], t); x[14] = csub(E[6], t);
    t = cmulc(O[7], W7); x[7] = cadd(E[7], t); x[15] = csub(E[7], t);
}

// One workgroup (256 thr) = TWO input rows (2b, 2b+1), pair-packed (v7b,
// verified). Dense float4 loads, Makhoul scatter to LDS, radix-16 Stockham
// (Ls = 1, 16, 256), Hermitian/expk epilogue -> FP16 stores.
// Output rows written PERMUTED for the column-Makhoul: 2b -> b, 2b+1 -> 4095-b.
__global__ __launch_bounds__(256) void dct_rows(const float* __restrict__ In,
                                                __half* __restrict__ Out,
                                                const float* __restrict__ tw,
                                                const float* __restrict__ ek) {
    __shared__ float2 buf[NF];   // 32 KB
    const int j = threadIdx.x;   // 0..255
    const int b = blockIdx.x;    // 0..2047
    const float* in0 = In + (size_t)(2 * b) * NF;
    const float* in1 = in0 + NF;
    __half* out0 = Out + (size_t)b * NF;            // sigma^-1(2b)   = b
    __half* out1 = Out + (size_t)(4095 - b) * NF;   // sigma^-1(2b+1) = 4095-b

    // ---- gather: dense float4 loads, Makhoul scatter into LDS
    const float4* i40 = (const float4*)in0;
    const float4* i41 = (const float4*)in1;
    #pragma unroll
    for (int c = 0; c < 4; ++c) {
        float4 a0 = i40[j + 256 * c];
        float4 a1 = i41[j + 256 * c];
        int nb = 2 * j + 512 * c;              // = 2*ch, ch = j+256c
        float2 z0; z0.x = a0.x; z0.y = a1.x;   // even -> n = nb
        float2 z1; z1.x = a0.z; z1.y = a1.z;   // even -> n = nb+1
        float2 z2; z2.x = a0.y; z2.y = a1.y;   // odd  -> 4095-nb
        float2 z3; z3.x = a0.w; z3.y = a1.w;   // odd  -> 4094-nb
        buf[physi(nb)]        = z0;
        buf[physi(nb + 1)]    = z1;
        buf[physi(4095 - nb)] = z2;
        buf[physi(4094 - nb)] = z3;
    }
    __syncthreads();

    float2 x[16];

    // ---- stage 0 (Ls=1): read j+256k from LDS, DFT16, write 16j+i
    #pragma unroll
    for (int k = 0; k < 16; ++k)
        x[k] = buf[physi(j + 256 * k)];
    dft16(x);
    __syncthreads();
    #pragma unroll
    for (int i = 0; i < 16; ++i)
        buf[physi(16 * j + i)] = x[i];
    __syncthreads();

    // ---- stage 1 (Ls=16): read j+256k, twiddle, DFT16, write p+256q+16i
    {
        const int p = j & 15, q = j >> 4;
        #pragma unroll
        for (int k = 0; k < 16; ++k)
            x[k] = buf[physi(j + 256 * k)];
        const float2* twp = (const float2*)tw + 64 + p * 16;
        #pragma unroll
        for (int k = 1; k < 16; ++k)
            x[k] = cmulc(x[k], twp[k]);
        dft16(x);
        __syncthreads();
        int wb = p + 256 * q;
        #pragma unroll
        for (int i = 0; i < 16; ++i)
            buf[physi(wb + 16 * i)] = x[i];
        __syncthreads();
    }

    // ---- stage 2 (Ls=256, p=j): read/write own slots j+256i, no mid barrier
    {
        #pragma unroll
        for (int k = 0; k < 16; ++k)
            x[k] = buf[physi(j + 256 * k)];
        const float2* twp = (const float2*)tw + 320 + j * 16;
        #pragma unroll
        for (int k = 1; k < 16; ++k)
            x[k] = cmulc(x[k], twp[k]);
        dft16(x);
        #pragma unroll
        for (int i = 0; i < 16; ++i)
            buf[physi(j + 256 * i)] = x[i];   // own slots only
    }
    __syncthreads();

    // ---- epilogue: Zk from regs; partner Zm via LDS; fp16 stores
    #pragma unroll
    for (int i = 0; i < 16; ++i) {
        int k = j + 256 * i;
        int m = (NF - k) & (NF - 1);
        float2 Zk = x[i];
        float2 Zm = buf[physi(m)];
        float2 E = ((const float2*)ek)[k];
        out0[k] = __float2half(0.5f * ((Zk.x + Zm.x) * E.x + (Zk.y - Zm.y) * E.y));
        out1[k] = __float2half(0.5f * ((Zk.y + Zm.y) * E.x - (Zk.x - Zm.x) * E.y));
    }
}

// ---------------------------------------------------------------------------
// Fused column pass (v9 structure, fp16 input): one block = 4 complex columns
// (real cols [8ct, 8ct+8)) x all 4096 rows in 128 KB dynamic LDS. 1024 thr:
// c = t&3 (complex column), j = t>>2 (butterfly job 0..255). Scatter reads
// uint2 = 4 halfs (8 B/lane, 16 B/row/block); 3 radix-16 stages; Hermitian/
// expk epilogue; fp32 float2 stores to Out. V rows already column-Makhoul-
// permuted by dct_rows, so this is a straight FFT over the row index.
// ---------------------------------------------------------------------------
__global__ __launch_bounds__(1024) void col_dct(const __half* __restrict__ V,
                                                float* __restrict__ Out,
                                                const float* __restrict__ tw,
                                                const float* __restrict__ ek) {
    extern __shared__ float2 buf[];   // 16384 float2 = 128 KB
    const int t = threadIdx.x;
    // chunked XCD swizzle: each XCD gets 64 consecutive column groups.
    const int bi = blockIdx.x;                 // 0..511
    const int ct = (bi & 7) * 64 + (bi >> 3);  // bijective (512 = 8*64)
    const int c = t & 3;                       // complex column 0..3
    const int j = t >> 2;                      // butterfly job 0..255

    // ---- scatter: rows (t>>1) + 512k, uint2 half-group h = t&1 -> LDS
    {
        const int h = t & 1, r0 = t >> 1;
        #pragma unroll
        for (int k = 0; k < 8; ++k) {
            int r = r0 + 512 * k;
            uint2 v = *(const uint2*)(V + (size_t)r * NF + 8 * ct + 4 * h);
            float2 a = __half22float2(*(__half2*)&v.x);   // complex 2h
            float2 d = __half22float2(*(__half2*)&v.y);   // complex 2h+1
            buf[cfi(r, 2 * h)]     = a;
            buf[cfi(r, 2 * h + 1)] = d;
        }
    }
    __syncthreads();

    float2 x[16];

    // ---- stage 0 (Ls=1): read j+256k, DFT16, write 16j+i
    #pragma unroll
    for (int k = 0; k < 16; ++k)
        x[k] = buf[cfi(j + 256 * k, c)];
    dft16(x);
    __syncthreads();
    #pragma unroll
    for (int i = 0; i < 16; ++i)
        buf[cfi(16 * j + i, c)] = x[i];
    __syncthreads();

    // ---- stage 1 (Ls=16): read j+256k, twiddle, DFT16, write p+256q+16i
    {
        const int p = j & 15, q = j >> 4;
        #pragma unroll
        for (int k = 0; k < 16; ++k)
            x[k] = buf[cfi(j + 256 * k, c)];
        const float2* twp = (const float2*)tw + 64 + p * 16;
        #pragma unroll
        for (int k = 1; k < 16; ++k)
            x[k] = cmulc(x[k], twp[k]);
        dft16(x);
        __syncthreads();
        int wb = p + 256 * q;
        #pragma unroll
        for (int i = 0; i < 16; ++i)
            buf[cfi(wb + 16 * i, c)] = x[i];
        __syncthreads();
    }

    // ---- stage 2 (Ls=256, p=j): read/write own slots j+256i
    {
        #pragma unroll
        for (int k = 0; k < 16; ++k)
            x[k] = buf[cfi(j + 256 * k, c)];
        const float2* twp = (const float2*)tw + 320 + j * 16;
        #pragma unroll
        for (int k = 1; k < 16; ++k)
            x[k] = cmulc(x[k], twp[k]);
        dft16(x);
        #pragma unroll
        for (int i = 0; i < 16; ++i)
            buf[cfi(j + 256 * i, c)] = x[i];   // own slots only
    }
    __syncthreads();

    // ---- epilogue: Zk from regs, partner Zm via LDS; fp32 float2 stores
    float* base = Out + 8 * (size_t)ct;
    #pragma unroll
    for (int i = 0; i < 16; ++i) {
        int k = j + 256 * i;
        int m = (NF - k) & (NF - 1);
        float2 Zk = x[i];
        float2 Zm = buf[cfi(m, c)];
        float2 E = ((const float2*)ek)[k];
        float2 r;
        r.x = 0.5f * ((Zk.x + Zm.x) * E.x + (Zk.y - Zm.y) * E.y);
        r.y = 0.5f * ((Zk.y + Zm.y) * E.x - (Zk.x - Zm.x) * E.y);
        *(float2*)&base[(size_t)k * NF + 2 * c] = r;
    }
}

extern "C" void kernel_launch(void* const* d_in, const int* in_sizes, int n_in,
                              void* d_out, int out_size, void* d_ws, size_t ws_size,
                              hipStream_t stream) {
    const float* x = (const float*)d_in[0];
    float* out = (float*)d_out;

    float* tw = (float*)d_ws;           // 4416 float2 = 8832 floats
    float* ek = tw + 8832;              // 4096 float2 = 8192 floats
    __half* V = (__half*)(ek + 8192);   // 4096*4096 halfs (32 MB)
    if (ws_size < (size_t)68096 + (size_t)NF * NF * sizeof(__half)) return;

    static bool attr_done = false;
    if (!attr_done) {
        (void)hipFuncSetAttribute((const void*)col_dct,
                                  hipFuncAttributeMaxDynamicSharedMemorySize,
                                  131072);
        attr_done = true;
    }

    setup_tables<<<34, 256, 0, stream>>>(tw, ek);
    dct_rows<<<NF / 2, 256, 0, stream>>>(x, V, tw, ek);       // ws = V (fp16)
    col_dct<<<512, 1024, 131072, stream>>>(V, out, tw, ek);   // out = Z (fp32)
}

// Round 11
// 153.929 us; speedup vs baseline: 1.0486x; 1.0486x over previous
//
#include <hip/hip_runtime.h>
#include <hip/hip_fp16.h>
#include <stdint.h>

// ---------------------------------------------------------------------------
// 2D DCT-II (unnormalized, 4096x4096 fp32), FFT path, v12:
//   v10 3-kernel structure (best: 159.4 us) + FP16 H intermediate:
//   1. dct_rows : x  -> out (V fp16 in d_out's first 32 MB; column-Makhoul
//                  folded into output row index: 2b -> b, 2b+1 -> 4095-b)
//   2. col_fft1 : out -> B1 (per n1: 64-pt FFT over n2 + 4-step twiddle;
//                  H fp16 at row 64*k2+n1; 32 MB instead of 64)
//   3. col_fft2 : B1 -> out (per k2-pair: 64-pt FFT over n1, Hermitian
//                  pairs block-local, expk epilogue, fp32 final Z)
//   Array traffic 320 -> 256 MB. v11's fused col_dct reverted: 128 KB LDS
//   = 1 block/CU = latency-serial (45 us) vs split kernels ~22 us each.
//   |H| <~ 2e3 << fp16 range; added error ~2 absolute (absmax 64, thr 231.7).
// ---------------------------------------------------------------------------

#define NF 4096

__device__ __forceinline__ int physi(int e) { return e ^ ((e >> 4) & 15); }

__device__ __forceinline__ float2 cadd(float2 a, float2 b) {
    float2 r; r.x = a.x + b.x; r.y = a.y + b.y; return r;
}
__device__ __forceinline__ float2 csub(float2 a, float2 b) {
    float2 r; r.x = a.x - b.x; r.y = a.y - b.y; return r;
}
__device__ __forceinline__ float2 cmulc(float2 a, float2 b) {
    float2 r; r.x = a.x * b.x - a.y * b.y; r.y = a.x * b.y + a.y * b.x; return r;
}
__device__ __forceinline__ float2 rotm(float2 a) {  // -i * a
    float2 r; r.x = a.y; r.y = -a.x; return r;
}

// tw layout (float2 units):
//   [0,64)      radix-8 Ls=8 table  w[p][u] = exp(-2pi*i*p*u/64)   (col FFTs)
//   [64,320)    radix-16 stage-1    w[p][u] = exp(-2pi*i*p*u/256)  p,u<16
//   [320,4416)  radix-16 stage-2    w[p][u] = exp(-2pi*i*p*u/4096) p<256,u<16
// ek: expk[k] = (cos(pi*k/8192), sin(pi*k/8192)), 4096 entries.
__global__ __launch_bounds__(256) void setup_tables(float* __restrict__ tw,
                                                    float* __restrict__ ek) {
    int idx = blockIdx.x * 256 + threadIdx.x;
    if (idx < 4416) {
        int p, u; float denom;
        if (idx < 64)       { p = idx >> 3;         u = idx & 7;  denom = 64.0f; }
        else if (idx < 320) { int r = idx - 64;  p = r >> 4; u = r & 15; denom = 256.0f; }
        else                { int r = idx - 320; p = r >> 4; u = r & 15; denom = 4096.0f; }
        float phi = (float)(p * u) * (6.283185307179586f / denom);
        float s, c; __sincosf(phi, &s, &c);
        tw[2 * idx]     = c;
        tw[2 * idx + 1] = -s;
    } else if (idx < 8512) {
        int k = idx - 4416;
        float th = (float)k * (3.141592653589793f / 8192.0f);
        float s, c; __sincosf(th, &s, &c);
        ek[2 * k]     = c;
        ek[2 * k + 1] = s;
    }
}

#define RADIX8(Xv, E0, E1, E2, E3, O0, g1, g2, g3)                             \
    float2 t0 = cadd(Xv[0], Xv[4]), t1 = csub(Xv[0], Xv[4]);                   \
    float2 t2 = cadd(Xv[2], Xv[6]), t3 = csub(Xv[2], Xv[6]);                   \
    float2 E0 = cadd(t0, t2), E2 = csub(t0, t2);                               \
    float2 r3 = rotm(t3);                                                      \
    float2 E1 = cadd(t1, r3), E3 = csub(t1, r3);                               \
    float2 s0 = cadd(Xv[1], Xv[5]), s1 = csub(Xv[1], Xv[5]);                   \
    float2 s2 = cadd(Xv[3], Xv[7]), s3 = csub(Xv[3], Xv[7]);                   \
    float2 O0 = cadd(s0, s2), O2 = csub(s0, s2);                               \
    float2 r7 = rotm(s3);                                                      \
    float2 O1 = cadd(s1, r7), O3 = csub(s1, r7);                               \
    const float SQ = 0.7071067811865476f;                                      \
    float2 g1; g1.x = SQ * (O1.x + O1.y); g1.y = SQ * (O1.y - O1.x);           \
    float2 g2 = rotm(O2);                                                      \
    float2 g3; g3.x = SQ * (O3.y - O3.x); g3.y = -SQ * (O3.x + O3.y);

// Full radix-8 butterfly to out[8] (self-scoped, reusable in one scope).
#define RADIX8_OUT(Xv, Ov)                                                     \
    {                                                                          \
        RADIX8(Xv, E0, E1, E2, E3, O0, g1, g2, g3)                             \
        Ov[0] = cadd(E0, O0); Ov[1] = cadd(E1, g1);                            \
        Ov[2] = cadd(E2, g2); Ov[3] = cadd(E3, g3);                            \
        Ov[4] = csub(E0, O0); Ov[5] = csub(E1, g1);                            \
        Ov[6] = csub(E2, g2); Ov[7] = csub(E3, g3);                            \
    }

// In-place 16-pt DFT: X[i] = E[i&7] +/- W16^i * O[i&7], E/O = DFT8(even/odd).
__device__ __forceinline__ void dft16(float2* x) {
    float2 E[8], O[8];
    {
        float2 a[8];
        #pragma unroll
        for (int m = 0; m < 8; ++m) a[m] = x[2 * m];
        RADIX8_OUT(a, E)
    }
    {
        float2 a[8];
        #pragma unroll
        for (int m = 0; m < 8; ++m) a[m] = x[2 * m + 1];
        RADIX8_OUT(a, O)
    }
    const float2 W1 = { 0.9238795325112867f, -0.3826834323650898f};
    const float2 W2 = { 0.7071067811865476f, -0.7071067811865476f};
    const float2 W3 = { 0.3826834323650898f, -0.9238795325112867f};
    const float2 W5 = {-0.3826834323650898f, -0.9238795325112867f};
    const float2 W6 = {-0.7071067811865476f, -0.7071067811865476f};
    const float2 W7 = {-0.9238795325112867f, -0.3826834323650898f};
    float2 t;
    x[0] = cadd(E[0], O[0]);  x[8]  = csub(E[0], O[0]);
    t = cmulc(O[1], W1); x[1] = cadd(E[1], t); x[9]  = csub(E[1], t);
    t = cmulc(O[2], W2); x[2] = cadd(E[2], t); x[10] = csub(E[2], t);
    t = cmulc(O[3], W3); x[3] = cadd(E[3], t); x[11] = csub(E[3], t);
    t = rotm(O[4]);      x[4] = cadd(E[4], t); x[12] = csub(E[4], t);
    t = cmulc(O[5], W5); x[5] = cadd(E[5], t); x[13] = csub(E[5], t);
    t = cmulc(O[6], W6); x[6] = cadd(E[6], t); x[14] = csub(E[6], t);
    t = cmulc(O[7], W7); x[7] = cadd(E[7], t); x[15] = csub(E[7], t);
}

// One workgroup (256 thr) = TWO input rows (2b, 2b+1), pair-packed (v7b,
// verified). Dense float4 loads, Makhoul scatter to LDS, radix-16 Stockham
// (Ls = 1, 16, 256), Hermitian/expk epilogue -> FP16 stores.
// Output rows written PERMUTED for the column-Makhoul: 2b -> b, 2b+1 -> 4095-b.
__global__ __launch_bounds__(256) void dct_rows(const float* __restrict__ In,
                                                __half* __restrict__ Out,
                                                const float* __restrict__ tw,
                                                const float* __restrict__ ek) {
    __shared__ float2 buf[NF];   // 32 KB
    const int j = threadIdx.x;   // 0..255
    const int b = blockIdx.x;    // 0..2047
    const float* in0 = In + (size_t)(2 * b) * NF;
    const float* in1 = in0 + NF;
    __half* out0 = Out + (size_t)b * NF;            // sigma^-1(2b)   = b
    __half* out1 = Out + (size_t)(4095 - b) * NF;   // sigma^-1(2b+1) = 4095-b

    // ---- gather: dense float4 loads, Makhoul scatter into LDS
    const float4* i40 = (const float4*)in0;
    const float4* i41 = (const float4*)in1;
    #pragma unroll
    for (int c = 0; c < 4; ++c) {
        float4 a0 = i40[j + 256 * c];
        float4 a1 = i41[j + 256 * c];
        int nb = 2 * j + 512 * c;              // = 2*ch, ch = j+256c
        float2 z0; z0.x = a0.x; z0.y = a1.x;   // even -> n = nb
        float2 z1; z1.x = a0.z; z1.y = a1.z;   // even -> n = nb+1
        float2 z2; z2.x = a0.y; z2.y = a1.y;   // odd  -> 4095-nb
        float2 z3; z3.x = a0.w; z3.y = a1.w;   // odd  -> 4094-nb
        buf[physi(nb)]        = z0;
        buf[physi(nb + 1)]    = z1;
        buf[physi(4095 - nb)] = z2;
        buf[physi(4094 - nb)] = z3;
    }
    __syncthreads();

    float2 x[16];

    // ---- stage 0 (Ls=1): read j+256k from LDS, DFT16, write 16j+i
    #pragma unroll
    for (int k = 0; k < 16; ++k)
        x[k] = buf[physi(j + 256 * k)];
    dft16(x);
    __syncthreads();
    #pragma unroll
    for (int i = 0; i < 16; ++i)
        buf[physi(16 * j + i)] = x[i];
    __syncthreads();

    // ---- stage 1 (Ls=16): read j+256k, twiddle, DFT16, write p+256q+16i
    {
        const int p = j & 15, q = j >> 4;
        #pragma unroll
        for (int k = 0; k < 16; ++k)
            x[k] = buf[physi(j + 256 * k)];
        const float2* twp = (const float2*)tw + 64 + p * 16;
        #pragma unroll
        for (int k = 1; k < 16; ++k)
            x[k] = cmulc(x[k], twp[k]);
        dft16(x);
        __syncthreads();
        int wb = p + 256 * q;
        #pragma unroll
        for (int i = 0; i < 16; ++i)
            buf[physi(wb + 16 * i)] = x[i];
        __syncthreads();
    }

    // ---- stage 2 (Ls=256, p=j): read/write own slots j+256i, no mid barrier
    {
        #pragma unroll
        for (int k = 0; k < 16; ++k)
            x[k] = buf[physi(j + 256 * k)];
        const float2* twp = (const float2*)tw + 320 + j * 16;
        #pragma unroll
        for (int k = 1; k < 16; ++k)
            x[k] = cmulc(x[k], twp[k]);
        dft16(x);
        #pragma unroll
        for (int i = 0; i < 16; ++i)
            buf[physi(j + 256 * i)] = x[i];   // own slots only
    }
    __syncthreads();

    // ---- epilogue: Zk from regs; partner Zm via LDS; fp16 stores
    #pragma unroll
    for (int i = 0; i < 16; ++i) {
        int k = j + 256 * i;
        int m = (NF - k) & (NF - 1);
        float2 Zk = x[i];
        float2 Zm = buf[physi(m)];
        float2 E = ((const float2*)ek)[k];
        out0[k] = __float2half(0.5f * ((Zk.x + Zm.x) * E.x + (Zk.y - Zm.y) * E.y));
        out1[k] = __float2half(0.5f * ((Zk.y + Zm.y) * E.x - (Zk.x - Zm.x) * E.y));
    }
}

// ---------------------------------------------------------------------------
// Column pass, four-step step 1 (fp16 in, fp16 out): TWO column-pairs per
// thread. One block = one n1 residue (blockIdx.y) x one 128-real-column tile
// (blockIdx.x, 0..31). 256 threads: g = ct*32 + (t&31) handles complex pairs
// {2g, 2g+1}; j = t>>5 is the butterfly job. Reads V rows n1+64*n2 as uint2
// (4 halfs), two independent 64-pt FFTs, four-step twiddle from a 64-entry
// LDS table, uint2 (4-half) stores of H to S row 64*k2+n1.
// ---------------------------------------------------------------------------
__global__ __launch_bounds__(256) void col_fft1(const __half* __restrict__ V,
                                                __half* __restrict__ S,
                                                const float* __restrict__ tw) {
    __shared__ float2 T[64][64];   // 32 KB: [row][col-pair]
    __shared__ float2 w64[64];
    const int ct = blockIdx.x, n1 = blockIdx.y;
    const int t = threadIdx.x;
    const int cp4 = t & 31, j = t >> 5;
    const int g = ct * 32 + cp4;                     // 0..1023
    const uint2* in2 = (const uint2*)V + g;          // row stride 1024 uint2

    if (t < 64) {
        int m = (n1 * t) & 4095;
        float phi = (float)m * -1.5339807878856412e-3f;  // -2pi/4096
        float s, c; __sincosf(phi, &s, &c);
        float2 w; w.x = c; w.y = s;
        w64[t] = w;
    }

    float2 xA[8], xB[8];
    #pragma unroll
    for (int k = 0; k < 8; ++k) {
        uint2 v = in2[(size_t)(n1 + 64 * (j + 8 * k)) * 1024];
        xA[k] = __half22float2(*(__half2*)&v.x);   // complex 2g
        xB[k] = __half22float2(*(__half2*)&v.y);   // complex 2g+1
    }
    {   // stage A (Ls=1): outputs to LDS rows 8j+i, both pairs as one float4
        float2 rA[8], rB[8];
        RADIX8_OUT(xA, rA)
        RADIX8_OUT(xB, rB)
        #pragma unroll
        for (int i = 0; i < 8; ++i) {
            float4 w; w.x = rA[i].x; w.y = rA[i].y; w.z = rB[i].x; w.w = rB[i].y;
            *(float4*)&T[8 * j + i][2 * cp4] = w;
        }
    }
    __syncthreads();

    float2 oA[8], oB[8];
    {   // stage B (Ls=8): p=j, natural-order outputs k2 = j+8i
        #pragma unroll
        for (int k = 0; k < 8; ++k) {
            float4 v4 = *(const float4*)&T[j + 8 * k][2 * cp4];
            xA[k].x = v4.x; xA[k].y = v4.y;
            xB[k].x = v4.z; xB[k].y = v4.w;
        }
        const float2* twp = (const float2*)tw + j * 8;   // Ls=8 section
        #pragma unroll
        for (int k = 1; k < 8; ++k) {
            xA[k] = cmulc(xA[k], twp[k]);
            xB[k] = cmulc(xB[k], twp[k]);
        }
        RADIX8_OUT(xA, oA)
        RADIX8_OUT(xB, oB)
    }

    // four-step twiddle from LDS, store both pairs (fp16) to S row 64*k2+n1
    uint2* out2 = (uint2*)S + g;
    #pragma unroll
    for (int i = 0; i < 8; ++i) {
        int k2 = j + 8 * i;
        float2 hA = cmulc(oA[i], w64[k2]);
        float2 hB = cmulc(oB[i], w64[k2]);
        __half2 a2 = __floats2half2_rn(hA.x, hA.y);
        __half2 b2 = __floats2half2_rn(hB.x, hB.y);
        uint2 w; w.x = *(unsigned int*)&a2; w.y = *(unsigned int*)&b2;
        out2[(size_t)(64 * k2 + n1) * 1024] = w;
    }
}

// ---------------------------------------------------------------------------
// Column pass, four-step step 2 + Hermitian/expk epilogue (fp16 H input).
// One block = k2-pair {ga, gb} = {bp, 64-bp} (bp=0 -> {0,32}) x one
// 64-real-column tile. 512 threads: gi = t>>8 group, j = (t>>5)&7, cp = t&31.
// ---------------------------------------------------------------------------
__global__ __launch_bounds__(512) void col_fft2(const __half* __restrict__ S,
                                                float* __restrict__ Out,
                                                const float* __restrict__ tw,
                                                const float* __restrict__ ek) {
    __shared__ float2 T[2][64][32];   // 32 KB
    const int ct = blockIdx.x, bp = blockIdx.y;
    const int ga = bp, gb = (bp == 0) ? 32 : 64 - bp;
    const int t = threadIdx.x;
    const int cp = t & 31, j = (t >> 5) & 7, gi = t >> 8;
    const int g = gi ? gb : ga;
    // complex column index cc = ct*32+cp, row stride 2048 complexes (__half2)
    const __half2* inb = (const __half2*)S + (size_t)ct * 32 + cp;

    float2 x[8];
    #pragma unroll
    for (int k = 0; k < 8; ++k)
        x[k] = __half22float2(inb[(size_t)(64 * g + j + 8 * k) * 2048]);
    {   // stage A
        float2 r[8];
        RADIX8_OUT(x, r)
        #pragma unroll
        for (int i = 0; i < 8; ++i)
            T[gi][8 * j + i][cp] = r[i];
    }
    __syncthreads();

    float2 o[8];
    {   // stage B: read rows j+8k, write rows j+8i (same per-thread set)
        #pragma unroll
        for (int k = 0; k < 8; ++k)
            x[k] = T[gi][j + 8 * k][cp];
        const float2* twp = (const float2*)tw + j * 8;
        #pragma unroll
        for (int k = 1; k < 8; ++k)
            x[k] = cmulc(x[k], twp[k]);
        RADIX8_OUT(x, o)
        #pragma unroll
        for (int i = 0; i < 8; ++i)
            T[gi][j + 8 * i][cp] = o[i];
    }
    __syncthreads();

    // epilogue: k = 64*(j+8i)+g; partner m = (4096-k)&4095 is in this block
    float2* outb = (float2*)Out + (size_t)ct * 32 + cp;
    #pragma unroll
    for (int i = 0; i < 8; ++i) {
        int k = 64 * (j + 8 * i) + g;
        int m = (NF - k) & (NF - 1);
        int gp = m & 63, k1p = m >> 6;
        float2 Zk = o[i];
        float2 Zm = T[(gp == ga) ? 0 : 1][k1p][cp];
        float2 E = ((const float2*)ek)[k];
        float2 r;
        r.x = 0.5f * ((Zk.x + Zm.x) * E.x + (Zk.y - Zm.y) * E.y);
        r.y = 0.5f * ((Zk.y + Zm.y) * E.x - (Zk.x - Zm.x) * E.y);
        outb[(size_t)k * 2048] = r;   // cols 2*(ct*32+cp), +1
    }
}

extern "C" void kernel_launch(void* const* d_in, const int* in_sizes, int n_in,
                              void* d_out, int out_size, void* d_ws, size_t ws_size,
                              hipStream_t stream) {
    const float* x = (const float*)d_in[0];
    float* out = (float*)d_out;

    float* tw = (float*)d_ws;           // 4416 float2 = 8832 floats
    float* ek = tw + 8832;              // 4096 float2 = 8192 floats
    __half* B1h = (__half*)(ek + 8192); // 4096*4096 halfs (32 MB) for H
    if (ws_size < (size_t)68096 + (size_t)NF * NF * sizeof(__half)) return;

    setup_tables<<<34, 256, 0, stream>>>(tw, ek);
    // V (fp16) lives in the first 32 MB of d_out; col_fft2 later overwrites
    // d_out with the final fp32 result (V is dead after col_fft1).
    dct_rows<<<NF / 2, 256, 0, stream>>>(x, (__half*)out, tw, ek);
    col_fft1<<<dim3(32, 64), 256, 0, stream>>>((const __half*)out, B1h, tw);
    col_fft2<<<dim3(64, 32), 512, 0, stream>>>(B1h, out, tw, ek);
}